// Round 3
// baseline (3267.863 us; speedup 1.0000x reference)
//
#include <hip/hip_runtime.h>
#include <hip/hip_bf16.h>

#define B_   32
#define T_   2048
#define DIN  512
#define DM   1024
#define K_   64
#define BT   64
#define NC   (T_/BT)    // 32 chunks
#define MT   (DM/64)    // 16 m-tiles
#define LDSTR 68        // padded LDS row stride (floats)

typedef unsigned short u16;
typedef unsigned int   u32;

__device__ __forceinline__ float bf2f(u16 h) {
    return __uint_as_float(((u32)h) << 16);
}
__device__ __forceinline__ void bf2x2(u32 w, float& lo, float& hi) {
    lo = __uint_as_float(w << 16);
    hi = __uint_as_float(w & 0xffff0000u);
}
__device__ __forceinline__ u16 f2bf(float f) {   // round-to-nearest-even
    u32 u = __float_as_uint(f);
    u += 0x7fffu + ((u >> 16) & 1u);
    return (u16)(u >> 16);
}
__device__ __forceinline__ float softplusf(float z) {
    return fmaxf(z, 0.0f) + log1pf(expf(-fabsf(z)));
}

// ---- dtype-agnostic loaders -------------------------------------------------
template<bool BF16>
__device__ __forceinline__ float ld1(const void* p, size_t i) {
    if (BF16) return bf2f(((const u16*)p)[i]);
    else      return ((const float*)p)[i];
}
template<bool BF16>
__device__ __forceinline__ void ld2(const void* p, size_t i, float& a, float& b) {
    if (BF16) { u32 w = *(const u32*)((const u16*)p + i); bf2x2(w, a, b); }
    else      { float2 v = *(const float2*)((const float*)p + i); a = v.x; b = v.y; }
}
template<bool BF16>
__device__ __forceinline__ void ld8(const void* p, size_t i, float* a) {
    if (BF16) {
        uint4 v = *(const uint4*)((const u16*)p + i);
        bf2x2(v.x, a[0], a[1]); bf2x2(v.y, a[2], a[3]);
        bf2x2(v.z, a[4], a[5]); bf2x2(v.w, a[6], a[7]);
    } else {
        float4 v0 = *(const float4*)((const float*)p + i);
        float4 v1 = *(const float4*)((const float*)p + i + 4);
        a[0]=v0.x; a[1]=v0.y; a[2]=v0.z; a[3]=v0.w;
        a[4]=v1.x; a[5]=v1.y; a[6]=v1.z; a[7]=v1.w;
    }
}

// ---- device-side dtype sniff (block-uniform; needs blockDim.x >= 64) --------
// bf16 x: every u16 is a plausible small value (~64/64 pass).
// fp32 x: even u16s are low-mantissa noise (~38/64 pass). Threshold 56.
__device__ __forceinline__ bool sniff_is_bf16(const void* xraw) {
    __shared__ int flag_s;
    if (threadIdx.x < 64) {
        u16 w = ((const u16*)xraw)[threadIdx.x];
        float av = fabsf(bf2f(w));
        bool plausible = (av == 0.0f) || (av >= 9.094947e-13f && av <= 64.0f);
        unsigned long long m = __ballot(plausible ? 1 : 0);
        if (threadIdx.x == 0) flag_s = (__popcll(m) >= 56) ? 1 : 0;
    }
    __syncthreads();
    return flag_s != 0;
}

// ---------------------------------------------------------------------------
// zero-init the fp32 accumulator region inside d_out.
//   bf16 path: floats[0..31]  (bytes 0..127, parity region — overwritten later)
//   fp32 path: floats[64..95] (the add_pred slots themselves)
// ---------------------------------------------------------------------------
__global__ __launch_bounds__(64) void zero_accum_kernel(const void* x, void* out) {
    bool isbf = sniff_is_bf16(x);
    float* outf = (float*)out;
    if (threadIdx.x < 32) {
        if (isbf) outf[threadIdx.x] = 0.0f;
        else      outf[64 + threadIdx.x] = 0.0f;
    }
}

// ---------------------------------------------------------------------------
// Fused SSM: one block per (b, m-tile); iterate 32 t-chunks sequentially,
// scan state carried in registers. Ends with atomicAdd of the W_add partial
// into the fp32 accumulator region of d_out.
// ---------------------------------------------------------------------------
template<bool BF16>
__global__ __launch_bounds__(256) void fused_ssm_kernel(
    const void* __restrict__ x,
    const void* __restrict__ Wlam, const void* __restrict__ blam,
    const void* __restrict__ Wdelt, const void* __restrict__ bdelt,
    const void* __restrict__ Winp, const void* __restrict__ binp,
    const void* __restrict__ Wadd,
    void* __restrict__ out)
{
    if (sniff_is_bf16(x) != BF16) return;

    __shared__ __align__(16) float smem[8704];   // 34.8 KB, reused GEMM <-> scan

    const int mt  = blockIdx.x & 15;
    const int b   = blockIdx.x >> 4;
    const int tid = threadIdx.x;
    const int tx  = tid & 15;    // m = mt*64 + tx*4 + jj
    const int ty  = tid >> 4;    // t = ty*4 + ii

    float bl[4], bd[4], bi[4];
    #pragma unroll
    for (int jj = 0; jj < 4; jj++) {
        int m = mt*64 + tx*4 + jj;
        bl[jj] = ld1<BF16>(blam, m); bd[jj] = ld1<BF16>(bdelt, m); bi[jj] = ld1<BF16>(binp, m);
    }

    float* xsT = smem;               // [32][LDSTR] transposed x tile
    float* w3  = smem + 32*LDSTR;    // [3][32][LDSTR]
    float* alphaS = smem;            // [64][LDSTR] (scan reuse)
    float* driveS = smem + 64*LDSTR;

    const int t_s = tid >> 2;          // 0..63
    const int ko  = (tid & 3) * 8;     // 0,8,16,24
    const int wk  = tid >> 3;          // 0..31
    const int wmo = (tid & 7) * 8;     // 0..56

    float scarry = 0.0f;

    for (int c = 0; c < NC; c++) {
        float acc0[4][4], acc1[4][4], acc2[4][4];
        #pragma unroll
        for (int ii = 0; ii < 4; ii++)
            #pragma unroll
            for (int jj = 0; jj < 4; jj++) {
                acc0[ii][jj] = bl[jj]; acc1[ii][jj] = bd[jj]; acc2[ii][jj] = bi[jj];
            }

        const size_t xbase = ((size_t)b*T_ + (size_t)c*BT) * DIN;

        for (int kk0 = 0; kk0 < DIN; kk0 += 32) {
            {   // stage x (-> fp32, transposed so t is contiguous)
                float a[8];
                ld8<BF16>(x, xbase + (size_t)t_s*DIN + kk0 + ko, a);
                #pragma unroll
                for (int q = 0; q < 8; q++)
                    xsT[(ko + q)*LDSTR + t_s] = a[q];
            }
            #pragma unroll
            for (int mat = 0; mat < 3; mat++) {   // stage 3 weight tiles
                const void* Wp = (mat == 0) ? Wlam : (mat == 1) ? Wdelt : Winp;
                float a[8];
                ld8<BF16>(Wp, (size_t)(kk0 + wk)*DM + mt*64 + wmo, a);
                float* dst = &w3[(mat*32 + wk)*LDSTR + wmo];
                *(float4*)(dst)     = make_float4(a[0],a[1],a[2],a[3]);
                *(float4*)(dst + 4) = make_float4(a[4],a[5],a[6],a[7]);
            }
            __syncthreads();

            #pragma unroll 8
            for (int kkk = 0; kkk < 32; kkk++) {
                float4 xa = *(const float4*)&xsT[kkk*LDSTR + ty*4];
                float4 w0 = *(const float4*)&w3[( 0 + kkk)*LDSTR + tx*4];
                float4 w1 = *(const float4*)&w3[(32 + kkk)*LDSTR + tx*4];
                float4 w2 = *(const float4*)&w3[(64 + kkk)*LDSTR + tx*4];
                float xv[4]  = {xa.x, xa.y, xa.z, xa.w};
                float w0v[4] = {w0.x, w0.y, w0.z, w0.w};
                float w1v[4] = {w1.x, w1.y, w1.z, w1.w};
                float w2v[4] = {w2.x, w2.y, w2.z, w2.w};
                #pragma unroll
                for (int ii = 0; ii < 4; ii++)
                    #pragma unroll
                    for (int jj = 0; jj < 4; jj++) {
                        acc0[ii][jj] = fmaf(xv[ii], w0v[jj], acc0[ii][jj]);
                        acc1[ii][jj] = fmaf(xv[ii], w1v[jj], acc1[ii][jj]);
                        acc2[ii][jj] = fmaf(xv[ii], w2v[jj], acc2[ii][jj]);
                    }
            }
            __syncthreads();
        }

        // activations -> alpha/drive into LDS
        #pragma unroll
        for (int ii = 0; ii < 4; ii++) {
            int t = ty*4 + ii;
            float a[4], d[4];
            #pragma unroll
            for (int jj = 0; jj < 4; jj++) {
                float lam = softplusf(acc0[ii][jj]);
                float dl  = softplusf(acc1[ii][jj]);
                a[jj] = expf(-dl * lam);
                d[jj] = dl * acc2[ii][jj];
            }
            *(float4*)&alphaS[t*LDSTR + tx*4] = make_float4(a[0],a[1],a[2],a[3]);
            *(float4*)&driveS[t*LDSTR + tx*4] = make_float4(d[0],d[1],d[2],d[3]);
        }
        __syncthreads();

        if (tid < 64) {   // in-chunk scan, one thread per m column
            float s = scarry;
            #pragma unroll 8
            for (int t = 0; t < BT; t++)
                s = fmaf(alphaS[t*LDSTR + tid], s, driveS[t*LDSTR + tid]);
            scarry = s;
        }
        __syncthreads();
    }

    // partial add_pred: dot with W_add, wave-reduce, one atomic per block
    if (tid < 64) {
        float partial = scarry * ld1<BF16>(Wadd, mt*64 + tid);
        #pragma unroll
        for (int off = 32; off > 0; off >>= 1)
            partial += __shfl_down(partial, off, 64);
        if (tid == 0) {
            float* outf = (float*)out;
            atomicAdd(BF16 ? &outf[b] : &outf[64 + b], partial);
        }
    }
}

// ---------------------------------------------------------------------------
// add_pred finalize: fold accumulator + bias, write in output dtype.
// Must run AFTER both fused variants, BEFORE parity (bf16 path reuses bytes).
// ---------------------------------------------------------------------------
template<bool BF16>
__global__ __launch_bounds__(64) void add_finalize_kernel(
    const void* x, const void* badd, void* out)
{
    if (sniff_is_bf16(x) != BF16) return;
    float bb = ld1<BF16>(badd, 0);
    if (threadIdx.x < 32) {
        float* outf = (float*)out;
        if (BF16) {
            float s = outf[threadIdx.x] + bb;      // accum in floats[0..31]
            ((u16*)out)[64 + threadIdx.x] = f2bf(s);
        } else {
            outf[64 + threadIdx.x] += bb;
        }
    }
}

// ---------------------------------------------------------------------------
// Parity: ang = pi*((sum_t x)·W_theta + T*b_theta); cos/sin; @ W_par.
// One block per batch, 256 threads. Runs LAST (overwrites bf16 accum bytes).
// ---------------------------------------------------------------------------
template<bool BF16>
__global__ __launch_bounds__(256) void parity_kernel(
    const void* __restrict__ x, const void* __restrict__ Wth, const void* __restrict__ bth,
    const void* __restrict__ Wpar, const void* __restrict__ bpar, void* __restrict__ out)
{
    if (sniff_is_bf16(x) != BF16) return;

    __shared__ float xsL[512];
    __shared__ float red[256];
    __shared__ float cosL[64], sinL[64];
    const int b = blockIdx.x;
    const int tid = threadIdx.x;

    // column sums: thread owns columns (2*tid, 2*tid+1)
    {
        float s0 = 0.0f, s1 = 0.0f;
        const size_t xb = (size_t)b * T_ * DIN;
        for (int t = 0; t < T_; t++) {
            float a, c2;
            ld2<BF16>(x, xb + (size_t)t*DIN + 2*tid, a, c2);
            s0 += a; s1 += c2;
        }
        xsL[2*tid] = s0; xsL[2*tid + 1] = s1;
    }
    __syncthreads();

    // theta matmul: tid = seg*64 + k, 128-wide partial dots
    {
        const int k = tid & 63, seg = tid >> 6;   // seg in 0..3
        float s = 0.0f;
        #pragma unroll 8
        for (int dd = 0; dd < 128; dd++) {
            int d = seg*128 + dd;
            s = fmaf(xsL[d], ld1<BF16>(Wth, (size_t)d*K_ + k), s);
        }
        red[tid] = s;
    }
    __syncthreads();

    if (tid < 64) {
        float s = red[tid] + red[64 + tid] + red[128 + tid] + red[192 + tid];
        float ang = 3.14159265358979323846f * (s + 2048.0f * ld1<BF16>(bth, tid));
        cosL[tid] = cosf(ang);
        sinL[tid] = sinf(ang);
    }
    __syncthreads();

    if (tid < 2) {
        const int j = tid;
        float s = ld1<BF16>(bpar, j);
        for (int k = 0; k < 64; k++) {
            s = fmaf(cosL[k], ld1<BF16>(Wpar, k*2 + j), s);
            s = fmaf(sinL[k], ld1<BF16>(Wpar, (64 + k)*2 + j), s);
        }
        if (BF16) ((u16*)out)[b*2 + j] = f2bf(s);
        else      ((float*)out)[b*2 + j] = s;
    }
}

extern "C" void kernel_launch(void* const* d_in, const int* in_sizes, int n_in,
                              void* d_out, int out_size, void* d_ws, size_t ws_size,
                              hipStream_t stream)
{
    const void* x     = d_in[0];
    const void* Wth   = d_in[1];
    const void* bth   = d_in[2];
    const void* Wlam  = d_in[3];
    const void* blam  = d_in[4];
    const void* Wdelt = d_in[5];
    const void* bdelt = d_in[6];
    const void* Winp  = d_in[7];
    const void* binp  = d_in[8];
    const void* Wpar  = d_in[9];
    const void* bpar  = d_in[10];
    const void* Wadd  = d_in[11];
    const void* badd  = d_in[12];
    (void)d_ws; (void)ws_size;   // workspace deliberately unused

    zero_accum_kernel<<<1, 64, 0, stream>>>(x, d_out);

    fused_ssm_kernel<true ><<<B_*MT, 256, 0, stream>>>(
        x, Wlam, blam, Wdelt, bdelt, Winp, binp, Wadd, d_out);
    fused_ssm_kernel<false><<<B_*MT, 256, 0, stream>>>(
        x, Wlam, blam, Wdelt, bdelt, Winp, binp, Wadd, d_out);

    add_finalize_kernel<true ><<<1, 64, 0, stream>>>(x, badd, d_out);
    add_finalize_kernel<false><<<1, 64, 0, stream>>>(x, badd, d_out);

    parity_kernel<true ><<<B_, 256, 0, stream>>>(x, Wth, bth, Wpar, bpar, d_out);
    parity_kernel<false><<<B_, 256, 0, stream>>>(x, Wth, bth, Wpar, bpar, d_out);
}